// Round 4
// baseline (1893.445 us; speedup 1.0000x reference)
//
#include <hip/hip_runtime.h>
#include <hip/hip_bf16.h>
#include <cstdio>

typedef unsigned int  u32;
typedef unsigned short u16;
typedef __attribute__((ext_vector_type(8))) short bf16x8;
typedef __attribute__((ext_vector_type(4))) float f32x4;

__device__ __forceinline__ float bfbits(u32 u){ union{u32 i; float f;} v; v.i=u; return v.f; }
__device__ __forceinline__ float bf2f(u16 u){ return bfbits(((u32)u)<<16); }
__device__ __forceinline__ u16 f2bf(float f){
  union{float f; u32 i;} v; v.f=f;
  u32 r = v.i + 0x7FFFu + ((v.i>>16)&1u);
  return (u16)(r>>16);
}
__device__ __forceinline__ int clampi(int v, int lo, int hi){ return v<lo?lo:(v>hi?hi:v); }

// ---------------- dtype detect: bf16 vs fp32 storage ----------------
// bf16 N(0,1) words: exponent field < 0x90, never exactly 0x0000.
// fp32 storage: low-half words have junk exponents (~44% >= 0x90) or are 0x0000
// (if values were bf16-rounded). Count over first 8192 words decides.
__global__ void detect_kernel(const u16* __restrict__ xr, int* __restrict__ flag){
  __shared__ int cnt;
  if (threadIdx.x==0) cnt=0;
  __syncthreads();
  int c=0;
  for (int i=threadIdx.x; i<8192; i+=256){
    u16 u = xr[i];
    int e = (u>>7)&0xFF;
    if (e>=0x90 || u==0) c++;
  }
  atomicAdd(&cnt, c);
  __syncthreads();
  if (threadIdx.x==0) *flag = (cnt>16) ? 1 : 0;   // 1 = fp32, 0 = bf16
}

__device__ __forceinline__ float rdin(const void* p, int idx, int f){
  return f ? ((const float*)p)[idx] : bf2f(((const u16*)p)[idx]);
}

// ---------------- canonicalize big tensors: x, edge_attr -> bf16 ----------------
__global__ void canon_big(const void* __restrict__ xr, const void* __restrict__ ear,
                          const int* __restrict__ flag,
                          ushort4* __restrict__ xbf, ushort4* __restrict__ eabf,
                          int NX4, int NE4){
  int f = *flag;
  int i = blockIdx.x*blockDim.x + threadIdx.x;
  if (i < NX4){
    if (f){ const float4 v = ((const float4*)xr)[i];
      ushort4 o; o.x=f2bf(v.x); o.y=f2bf(v.y); o.z=f2bf(v.z); o.w=f2bf(v.w);
      xbf[i]=o;
    } else xbf[i] = ((const ushort4*)xr)[i];
  } else if (i < NX4+NE4){
    int j = i - NX4;
    if (f){ const float4 v = ((const float4*)ear)[j];
      ushort4 o; o.x=f2bf(v.x); o.y=f2bf(v.y); o.z=f2bf(v.z); o.w=f2bf(v.w);
      eabf[j]=o;
    } else eabf[j] = ((const ushort4*)ear)[j];
  }
}

// ---------------- canonicalize small tensors + zero counters ----------------
__global__ void canon_small(const int* __restrict__ flag,
   const void* Wl0, const void* Wr0, const void* Wl1, const void* Wr1,
   const void* We0, const void* We1,
   const void* bl0, const void* br0, const void* bias0, const void* att0,
   const void* bl1, const void* br1, const void* bias1, const void* att1,
   const void* fc1b, const void* fc2W, const void* fc2b, const void* fc1W,
   u16* __restrict__ wbf, float* __restrict__ we0f, float* __restrict__ we1f,
   float* __restrict__ params, int* __restrict__ deg, float* __restrict__ pooled, int N)
{
  int f = *flag;
  int i = blockIdx.x*blockDim.x + threadIdx.x;
  if (i < N) deg[i] = 0;
  if (i < 8192) pooled[i] = 0.f;
  if (i < 32768){
    wbf[i]        = f2bf(rdin(Wl0,i,f));
    wbf[32768+i]  = f2bf(rdin(Wr0,i,f));
    wbf[65536+i]  = f2bf(rdin(Wl1,i,f));
    wbf[98304+i]  = f2bf(rdin(Wr1,i,f));
  }
  if (i < 4096) we0f[i] = rdin(We0,i,f);
  if (i < 2048) we1f[i] = rdin(We1,i,f);
  if (i < 256){ params[i]=rdin(bl0,i,f); params[256+i]=rdin(br0,i,f);
                params[512+i]=rdin(bias0,i,f); params[768+i]=rdin(att0,i,f); }
  if (i < 128){ params[1024+i]=rdin(bl1,i,f); params[1152+i]=rdin(br1,i,f);
                params[1280+i]=rdin(bias1,i,f); params[1408+i]=rdin(att1,i,f);
                params[1536+i]=rdin(fc1b,i,f); params[1664+i]=rdin(fc2W,i,f); }
  if (i == 0) params[1792] = rdin(fc2b,0,f);
  if (i < 16384) params[1800+i] = rdin(fc1W,i,f);
}

// ---------------- CSR build ----------------
__global__ void hist_kernel(const int* __restrict__ ei, int* __restrict__ deg, int E, int N){
  int e = blockIdx.x*blockDim.x + threadIdx.x;
  if (e < E) atomicAdd(&deg[clampi(ei[E+e],0,N-1)], 1);
}

// single-block scan; re-zeroes deg so it can serve as the fill counter
__global__ __launch_bounds__(1024) void scan_kernel(int* __restrict__ deg,
                                                    int* __restrict__ indptr, int n){
  __shared__ int lds[1024];
  __shared__ int carry_s;
  int t = threadIdx.x;
  if (t==0) carry_s = 0;
  __syncthreads();
  for (int base=0; base<n; base+=1024){
    int i = base+t;
    int v = 0;
    if (i<n){ v = deg[i]; deg[i] = 0; }
    lds[t] = v;
    __syncthreads();
    for (int off=1; off<1024; off<<=1){
      int add = (t>=off)? lds[t-off] : 0;
      __syncthreads();
      lds[t] += add;
      __syncthreads();
    }
    int incl  = lds[t];
    int carry = carry_s;
    int total = lds[1023];
    if (i<n) indptr[i] = carry + incl - v;
    __syncthreads();
    if (t==0) carry_s = carry + total;
    __syncthreads();
  }
  if (t==0) indptr[n] = carry_s;
}

__global__ void scatter_kernel(const int* __restrict__ ei, const int* __restrict__ indptr,
                               int* __restrict__ fill, int* __restrict__ sorted_eid, int E, int N){
  int e = blockIdx.x*blockDim.x + threadIdx.x;
  if (e < E){
    int d = clampi(ei[E+e], 0, N-1);
    int pos = clampi(indptr[d] + atomicAdd(&fill[d], 1), 0, E-1);
    sorted_eid[pos] = e;
  }
}

// ---------------- node transform GEMM (MFMA): XL = X@Wl+bl, XR = X@Wr+br ----------------
template<int K, int M>
__global__ __launch_bounds__(256) void node_gemm(
    const u16* __restrict__ X, const u16* __restrict__ Wl, const float* __restrict__ blf,
    const u16* __restrict__ Wr, const float* __restrict__ brf,
    u16* __restrict__ XL, u16* __restrict__ XR, int N)
{
  constexpr int KS = K/32;
  int wave = threadIdx.x >> 6, lane = threadIdx.x & 63;
  int ntile = blockIdx.y*4 + wave;
  int mtile = blockIdx.x;
  int m = mtile*16 + (lane & 15);
  if (m >= N) m = N-1;
  int kq = (lane >> 4) * 8;
  int col = ntile*16 + (lane & 15);         // [0, 2M); wave-uniform isR
  bool isR = (col >= M);
  int c = isR ? col - M : col;
  const u16* W = isR ? Wr : Wl;
  float bv = isR ? brf[c] : blf[c];
  u16* OUT = isR ? XR : XL;

  bf16x8 af[KS], bfr[KS];
  const u16* xrow = X + (size_t)m*K;
  #pragma unroll
  for (int s=0; s<KS; s++){
    af[s] = *(const bf16x8*)(xrow + s*32 + kq);                         // A[m][k]
    #pragma unroll
    for (int j=0; j<8; j++) bfr[s][j] = (short)W[(size_t)(s*32 + kq + j)*M + c]; // B[k][n]
  }
  f32x4 acc = {0.f,0.f,0.f,0.f};
  #pragma unroll
  for (int s=0; s<KS; s++)
    acc = __builtin_amdgcn_mfma_f32_16x16x32_bf16(af[s], bfr[s], acc, 0,0,0);
  #pragma unroll
  for (int r=0; r<4; r++){
    int node = mtile*16 + (lane>>4)*4 + r;            // C/D: row=quad*4+reg, col=lane&15
    if (node < N) OUT[(size_t)node*M + c] = f2bf(acc[r] + bv);
  }
}

// ---------------- edge score, layer 0 (M=256, H=4, C=64): wave per edge ----------------
__global__ __launch_bounds__(256) void score_l0_kernel(
    const int* __restrict__ ei, const u16* __restrict__ eattr,
    const float* __restrict__ We, const u16* __restrict__ xl,
    const u16* __restrict__ xr, const float* __restrict__ attf,
    float* __restrict__ score, int E, int N)
{
  int e = blockIdx.x*4 + (threadIdx.x>>6);
  if (e >= E) return;
  int lane = threadIdx.x & 63;
  int src = clampi(ei[e], 0, N-1), dst = clampi(ei[E+e], 0, N-1);
  float eaf[16];
  {
    const uint4* p = (const uint4*)(eattr + (size_t)e*16);
    uint4 u0 = p[0], u1 = p[1];
    u32 uu[8] = {u0.x,u0.y,u0.z,u0.w,u1.x,u1.y,u1.z,u1.w};
    #pragma unroll
    for (int i=0;i<8;i++){ eaf[2*i]=bfbits(uu[i]<<16); eaf[2*i+1]=bfbits(uu[i]&0xFFFF0000u); }
  }
  int c0 = lane*4;
  float v0,v1,v2,v3;
  {
    uint2 qa = *(const uint2*)(xl + (size_t)src*256 + c0);
    uint2 qb = *(const uint2*)(xr + (size_t)dst*256 + c0);
    v0 = bfbits(qa.x<<16)        + bfbits(qb.x<<16);
    v1 = bfbits(qa.x&0xFFFF0000u)+ bfbits(qb.x&0xFFFF0000u);
    v2 = bfbits(qa.y<<16)        + bfbits(qb.y<<16);
    v3 = bfbits(qa.y&0xFFFF0000u)+ bfbits(qb.y&0xFFFF0000u);
  }
  #pragma unroll
  for (int k=0;k<16;k++){
    const float4 wv = *(const float4*)(We + k*256 + c0);
    v0 += eaf[k]*wv.x; v1 += eaf[k]*wv.y; v2 += eaf[k]*wv.z; v3 += eaf[k]*wv.w;
  }
  int h = lane>>4;
  const float4 at = *(const float4*)(attf + h*64 + (c0 & 63));
  float p = (v0>0.f? v0:0.2f*v0)*at.x + (v1>0.f? v1:0.2f*v1)*at.y
          + (v2>0.f? v2:0.2f*v2)*at.z + (v3>0.f? v3:0.2f*v3)*at.w;
  p += __shfl_xor(p,1); p += __shfl_xor(p,2); p += __shfl_xor(p,4); p += __shfl_xor(p,8);
  if ((lane&15)==0) score[(size_t)e*4 + h] = p;
}

// ---------------- edge score, layer 1 (M=128, H=4, C=32) ----------------
__global__ __launch_bounds__(256) void score_l1_kernel(
    const int* __restrict__ ei, const u16* __restrict__ eattr,
    const float* __restrict__ We, const u16* __restrict__ xl,
    const u16* __restrict__ xr, const float* __restrict__ attf,
    float* __restrict__ score, int E, int N)
{
  int e = blockIdx.x*4 + (threadIdx.x>>6);
  if (e >= E) return;
  int lane = threadIdx.x & 63;
  int src = clampi(ei[e], 0, N-1), dst = clampi(ei[E+e], 0, N-1);
  float eaf[16];
  {
    const uint4* p = (const uint4*)(eattr + (size_t)e*16);
    uint4 u0 = p[0], u1 = p[1];
    u32 uu[8] = {u0.x,u0.y,u0.z,u0.w,u1.x,u1.y,u1.z,u1.w};
    #pragma unroll
    for (int i=0;i<8;i++){ eaf[2*i]=bfbits(uu[i]<<16); eaf[2*i+1]=bfbits(uu[i]&0xFFFF0000u); }
  }
  int c0 = lane*2;
  float v0,v1;
  {
    u32 qa = *(const u32*)(xl + (size_t)src*128 + c0);
    u32 qb = *(const u32*)(xr + (size_t)dst*128 + c0);
    v0 = bfbits(qa<<16)         + bfbits(qb<<16);
    v1 = bfbits(qa&0xFFFF0000u) + bfbits(qb&0xFFFF0000u);
  }
  #pragma unroll
  for (int k=0;k<16;k++){
    const float2 wv = *(const float2*)(We + k*128 + c0);
    v0 += eaf[k]*wv.x; v1 += eaf[k]*wv.y;
  }
  int h = lane>>4;
  const float2 at = *(const float2*)(attf + h*32 + (c0 & 31));
  float p = (v0>0.f? v0:0.2f*v0)*at.x + (v1>0.f? v1:0.2f*v1)*at.y;
  p += __shfl_xor(p,1); p += __shfl_xor(p,2); p += __shfl_xor(p,4); p += __shfl_xor(p,8);
  if ((lane&15)==0) score[(size_t)e*4 + h] = p;
}

// ---------------- aggregation: wave per node, fused softmax + bias + relu ----------------
template<int M>
__global__ __launch_bounds__(256) void agg_kernel(
    const int* __restrict__ indptr, const int* __restrict__ sorted_eid,
    const int* __restrict__ ei, const float* __restrict__ score,
    const u16* __restrict__ xl, const float* __restrict__ biasf,
    u16* __restrict__ outp, int N, int E)
{
  constexpr int VPT = M/64;
  int n = blockIdx.x*4 + (threadIdx.x>>6);
  if (n >= N) return;
  int lane = threadIdx.x & 63;
  int s0 = clampi(indptr[n], 0, E), s1 = clampi(indptr[n+1], s0, E);

  float m0=-1e30f,m1=-1e30f,m2=-1e30f,m3=-1e30f;
  for (int i=s0+lane; i<s1; i+=64){
    int e = clampi(sorted_eid[i], 0, E-1);
    const float4 sc = *(const float4*)(score + (size_t)e*4);
    m0=fmaxf(m0,sc.x); m1=fmaxf(m1,sc.y); m2=fmaxf(m2,sc.z); m3=fmaxf(m3,sc.w);
  }
  #pragma unroll
  for (int off=32; off>0; off>>=1){
    m0=fmaxf(m0,__shfl_xor(m0,off)); m1=fmaxf(m1,__shfl_xor(m1,off));
    m2=fmaxf(m2,__shfl_xor(m2,off)); m3=fmaxf(m3,__shfl_xor(m3,off));
  }
  float d0=0,d1=0,d2=0,d3=0;
  for (int i=s0+lane; i<s1; i+=64){
    int e = clampi(sorted_eid[i], 0, E-1);
    const float4 sc = *(const float4*)(score + (size_t)e*4);
    d0+=__expf(sc.x-m0); d1+=__expf(sc.y-m1); d2+=__expf(sc.z-m2); d3+=__expf(sc.w-m3);
  }
  #pragma unroll
  for (int off=32; off>0; off>>=1){
    d0+=__shfl_xor(d0,off); d1+=__shfl_xor(d1,off);
    d2+=__shfl_xor(d2,off); d3+=__shfl_xor(d3,off);
  }
  int h = lane>>4;
  float mh = (h==0)?m0:((h==1)?m1:((h==2)?m2:m3));
  float dh = ((h==0)?d0:((h==1)?d1:((h==2)?d2:d3))) + 1e-16f;
  float rdh = 1.f/dh;
  float acc[VPT];
  #pragma unroll
  for (int j=0;j<VPT;j++) acc[j]=0.f;
  int cb = lane*VPT;
  for (int i=s0; i<s1; i++){
    int e  = clampi(sorted_eid[i], 0, E-1);
    int sn = clampi(ei[e], 0, N-1);
    float a = __expf(score[(size_t)e*4 + h] - mh) * rdh;
    if constexpr (VPT == 4){
      uint2 q = *(const uint2*)(xl + (size_t)sn*M + cb);
      acc[0]+=a*bfbits(q.x<<16); acc[1]+=a*bfbits(q.x&0xFFFF0000u);
      acc[2]+=a*bfbits(q.y<<16); acc[3]+=a*bfbits(q.y&0xFFFF0000u);
    } else {
      u32 q = *(const u32*)(xl + (size_t)sn*M + cb);
      acc[0]+=a*bfbits(q<<16); acc[1]+=a*bfbits(q&0xFFFF0000u);
    }
  }
  #pragma unroll
  for (int j=0;j<VPT;j++){
    float o = acc[j] + biasf[cb+j];
    o = (o>0.f)? o : 0.f;
    outp[(size_t)n*M + cb + j] = f2bf(o);
  }
}

// ---------------- mean pool + MLP head, one block per graph ----------------
__device__ __forceinline__ int lower_bound_dev(const int* a, int n, int key){
  int lo=0, hi=n;
  while (lo<hi){ int mid=(lo+hi)>>1; if (a[mid] < key) lo=mid+1; else hi=mid; }
  return lo;
}

__global__ __launch_bounds__(128) void pool_mlp_kernel(
    const u16* __restrict__ h2, const int* __restrict__ batch,
    const float* __restrict__ params, const int* __restrict__ flag,
    void* __restrict__ out, int N)
{
  int g = blockIdx.x, t = threadIdx.x;   // 128 threads
  __shared__ int sh_lo, sh_hi;
  if (t==0) sh_lo = lower_bound_dev(batch, N, g);
  if (t==1) sh_hi = lower_bound_dev(batch, N, g+1);
  __syncthreads();
  int lo = clampi(sh_lo, 0, N), hi = clampi(sh_hi, lo, N);
  float s = 0.f;
  for (int n=lo; n<hi; n++) s += bf2f(h2[(size_t)n*128 + t]);
  float cnt = (float)(hi-lo);
  float pooled = s / fmaxf(cnt, 1.f);
  __shared__ float pl[128];
  pl[t] = pooled;
  __syncthreads();
  const float* fc1W = params + 1800;
  float z = 0.f;
  for (int k=0; k<128; k++) z += pl[k]*fc1W[k*128 + t];
  z += params[1536 + t];                 // fc1b
  z = (z>0.f)? z : 0.f;
  __shared__ float red[128];
  red[t] = z * params[1664 + t];         // fc2W
  __syncthreads();
  for (int st=64; st>0; st>>=1){
    if (t<st) red[t] += red[t+st];
    __syncthreads();
  }
  if (t==0){
    float zz = red[0] + params[1792];    // fc2b
    float r = 1.f/(1.f + __expf(-zz));
    if (*flag) ((float*)out)[g] = r;
    else       ((u16*)out)[g] = f2bf(r);
  }
}

// ---------------- launch ----------------
extern "C" void kernel_launch(void* const* d_in, const int* in_sizes, int n_in,
                              void* d_out, int out_size, void* d_ws, size_t ws_size,
                              hipStream_t stream)
{
  const void* x     = d_in[0];
  const void* eattr = d_in[1];
  const int*  ei    = (const int*)d_in[2];
  const int*  batch = (const int*)d_in[3];

  int N = in_sizes[0] / 128;   // 50000
  int E = in_sizes[2] / 2;     // 800000
  int G = out_size;            // 64

  fprintf(stderr, "[kern] ws=%zu\n", ws_size); fflush(stderr);

  // Workspace layout (256 MB available; peak used ~144.8 MB, no aliasing):
  char* w = (char*)d_ws;
  int*   flag   = (int*)(w);                     // [0,4)
  int*   deg    = (int*)(w + 256);               // N ints
  int*   indptr = (int*)(w + 200448);            // N+1
  int*   sorted = (int*)(w + 400512);            // E ints
  float* we0f   = (float*)(w + 3600640);         // 4096
  float* we1f   = (float*)(w + 3617024);         // 2048
  float* pooled = (float*)(w + 3625216);         // 8192 (unused this round; zeroed)
  float* params = (float*)(w + 3658240);         // 18184 f32
  u16*   wbf    = (u16*)(w + 3731200);           // 131072 bf16
  u16*   xbf    = (u16*)(w + 3993600);           // N*128
  u16*   eabf   = (u16*)(w + 16793600);          // E*16
  float* score  = (float*)(w + 42393600);        // E*4
  u16*   xl0    = (u16*)(w + 55193600);          // N*256 (layer1: N*128)
  u16*   xr0    = (u16*)(w + 80793600);          // N*256 (layer1: N*128)
  u16*   h1     = (u16*)(w + 106393600);         // N*256
  u16*   h2     = (u16*)(w + 131993600);         // N*128

  detect_kernel<<<1, 256, 0, stream>>>((const u16*)x, flag);

  int NX4 = N*128/4, NE4 = E*16/4;
  canon_big<<<(NX4+NE4+255)/256, 256, 0, stream>>>(x, eattr, flag,
      (ushort4*)xbf, (ushort4*)eabf, NX4, NE4);
  canon_small<<<(N+255)/256, 256, 0, stream>>>(flag,
      d_in[4], d_in[6], d_in[11], d_in[13],            // Wl0 Wr0 Wl1 Wr1
      d_in[8], d_in[15],                               // We0 We1
      d_in[5], d_in[7], d_in[10], d_in[9],             // bl0 br0 bias0 att0
      d_in[12], d_in[14], d_in[17], d_in[16],          // bl1 br1 bias1 att1
      d_in[19], d_in[20], d_in[21], d_in[18],          // fc1b fc2W fc2b fc1W
      wbf, we0f, we1f, params, deg, pooled, N);

  hist_kernel<<<(E+255)/256, 256, 0, stream>>>(ei, deg, E, N);
  scan_kernel<<<1, 1024, 0, stream>>>(deg, indptr, N);
  scatter_kernel<<<(E+255)/256, 256, 0, stream>>>(ei, indptr, deg, sorted, E, N);

  int mt = (N+15)/16;
  // layer 0
  node_gemm<128,256><<<dim3(mt, 8), 256, 0, stream>>>(xbf, wbf, params,
      wbf+32768, params+256, xl0, xr0, N);
  score_l0_kernel<<<(E+3)/4, 256, 0, stream>>>(ei, eabf, we0f, xl0, xr0,
      params+768, score, E, N);
  agg_kernel<256><<<(N+3)/4, 256, 0, stream>>>(indptr, sorted, ei, score, xl0,
      params+512, h1, N, E);

  // layer 1
  node_gemm<256,128><<<dim3(mt, 4), 256, 0, stream>>>(h1, wbf+65536, params+1024,
      wbf+98304, params+1152, xl0, xr0, N);
  score_l1_kernel<<<(E+3)/4, 256, 0, stream>>>(ei, eabf, we1f, xl0, xr0,
      params+1408, score, E, N);
  agg_kernel<128><<<(N+3)/4, 256, 0, stream>>>(indptr, sorted, ei, score, xl0,
      params+1280, h2, N, E);

  // pool + MLP + sigmoid
  pool_mlp_kernel<<<G, 128, 0, stream>>>(h2, batch, params, flag, d_out, N);
}

// Round 5
// 1362.829 us; speedup vs baseline: 1.3893x; 1.3893x over previous
//
#include <hip/hip_runtime.h>
#include <hip/hip_bf16.h>

typedef unsigned int  u32;
typedef unsigned short u16;
typedef __attribute__((ext_vector_type(8))) short bf16x8;
typedef __attribute__((ext_vector_type(4))) float f32x4;

__device__ __forceinline__ float bfbits(u32 u){ union{u32 i; float f;} v; v.i=u; return v.f; }
__device__ __forceinline__ float bf2f(u16 u){ return bfbits(((u32)u)<<16); }
__device__ __forceinline__ u16 f2bf(float f){
  union{float f; u32 i;} v; v.f=f;
  u32 r = v.i + 0x7FFFu + ((v.i>>16)&1u);
  return (u16)(r>>16);
}
__device__ __forceinline__ int clampi(int v, int lo, int hi){ return v<lo?lo:(v>hi?hi:v); }

__device__ __forceinline__ void load_eattr16(const u16* p, float* eaf){
  const uint4* q = (const uint4*)p;
  uint4 u0 = q[0], u1 = q[1];
  u32 uu[8] = {u0.x,u0.y,u0.z,u0.w,u1.x,u1.y,u1.z,u1.w};
  #pragma unroll
  for (int i=0;i<8;i++){ eaf[2*i]=bfbits(uu[i]<<16); eaf[2*i+1]=bfbits(uu[i]&0xFFFF0000u); }
}

// ---------------- dtype detect: bf16 vs fp32 storage (unchanged — verified r4) ----------------
__global__ void detect_kernel(const u16* __restrict__ xr, int* __restrict__ flag){
  __shared__ int cnt;
  if (threadIdx.x==0) cnt=0;
  __syncthreads();
  int c=0;
  for (int i=threadIdx.x; i<8192; i+=256){
    u16 u = xr[i];
    int e = (u>>7)&0xFF;
    if (e>=0x90 || u==0) c++;
  }
  atomicAdd(&cnt, c);
  __syncthreads();
  if (threadIdx.x==0) *flag = (cnt>16) ? 1 : 0;   // 1 = fp32, 0 = bf16
}

__device__ __forceinline__ float rdin(const void* p, int idx, int f){
  return f ? ((const float*)p)[idx] : bf2f(((const u16*)p)[idx]);
}

// ---------------- canonicalize big tensors: x, edge_attr -> bf16 ----------------
__global__ void canon_big(const void* __restrict__ xr, const void* __restrict__ ear,
                          const int* __restrict__ flag,
                          ushort4* __restrict__ xbf, ushort4* __restrict__ eabf,
                          int NX4, int NE4){
  int f = *flag;
  int i = blockIdx.x*blockDim.x + threadIdx.x;
  if (i < NX4){
    if (f){ const float4 v = ((const float4*)xr)[i];
      ushort4 o; o.x=f2bf(v.x); o.y=f2bf(v.y); o.z=f2bf(v.z); o.w=f2bf(v.w);
      xbf[i]=o;
    } else xbf[i] = ((const ushort4*)xr)[i];
  } else if (i < NX4+NE4){
    int j = i - NX4;
    if (f){ const float4 v = ((const float4*)ear)[j];
      ushort4 o; o.x=f2bf(v.x); o.y=f2bf(v.y); o.z=f2bf(v.z); o.w=f2bf(v.w);
      eabf[j]=o;
    } else eabf[j] = ((const ushort4*)ear)[j];
  }
}

// ---------------- canonicalize small tensors + zero counters ----------------
__global__ void canon_small(const int* __restrict__ flag,
   const void* Wl0, const void* Wr0, const void* Wl1, const void* Wr1,
   const void* We0, const void* We1,
   const void* bl0, const void* br0, const void* bias0, const void* att0,
   const void* bl1, const void* br1, const void* bias1, const void* att1,
   const void* fc1b, const void* fc2W, const void* fc2b, const void* fc1W,
   u16* __restrict__ wbf, float* __restrict__ we0f, float* __restrict__ we1f,
   float* __restrict__ params, int* __restrict__ deg, int N)
{
  int f = *flag;
  int i = blockIdx.x*blockDim.x + threadIdx.x;
  if (i < N) deg[i] = 0;
  if (i < 32768){
    wbf[i]        = f2bf(rdin(Wl0,i,f));
    wbf[32768+i]  = f2bf(rdin(Wr0,i,f));
    wbf[65536+i]  = f2bf(rdin(Wl1,i,f));
    wbf[98304+i]  = f2bf(rdin(Wr1,i,f));
  }
  if (i < 4096) we0f[i] = rdin(We0,i,f);
  if (i < 2048) we1f[i] = rdin(We1,i,f);
  if (i < 256){ params[i]=rdin(bl0,i,f); params[256+i]=rdin(br0,i,f);
                params[512+i]=rdin(bias0,i,f); params[768+i]=rdin(att0,i,f); }
  if (i < 128){ params[1024+i]=rdin(bl1,i,f); params[1152+i]=rdin(br1,i,f);
                params[1280+i]=rdin(bias1,i,f); params[1408+i]=rdin(att1,i,f);
                params[1536+i]=rdin(fc1b,i,f); params[1664+i]=rdin(fc2W,i,f); }
  if (i == 0) params[1792] = rdin(fc2b,0,f);
  if (i < 16384) params[1800+i] = rdin(fc1W,i,f);
}

// ---------------- CSR build ----------------
__global__ void hist_kernel(const int* __restrict__ ei, int* __restrict__ deg, int E, int N){
  int e = blockIdx.x*blockDim.x + threadIdx.x;
  if (e < E) atomicAdd(&deg[clampi(ei[E+e],0,N-1)], 1);
}

// chunked single-pass scan: thread t owns a contiguous chunk; serial scan +
// one 1024-wide block scan of chunk totals. Re-zeroes deg (fill reuse).
__global__ __launch_bounds__(1024) void scan_kernel(int* __restrict__ deg,
                                                    int* __restrict__ indptr, int n){
  __shared__ int lds[1024];
  int t = threadIdx.x;
  int chunk = (n + 1023)/1024;
  int lo = t*chunk, hi = lo+chunk; if (lo>n) lo=n; if (hi>n) hi=n;
  int sum=0;
  for (int i=lo;i<hi;i++) sum += deg[i];
  lds[t]=sum;
  __syncthreads();
  for (int off=1; off<1024; off<<=1){
    int add = (t>=off)? lds[t-off] : 0;
    __syncthreads();
    lds[t] += add;
    __syncthreads();
  }
  int run = lds[t]-sum;     // exclusive prefix of chunk
  for (int i=lo;i<hi;i++){
    int v = deg[i]; deg[i]=0;
    indptr[i]=run; run+=v;
  }
  if (lo<n && hi==n) indptr[n]=run;
}

__global__ void scatter_kernel(const int* __restrict__ ei, const int* __restrict__ indptr,
                               int* __restrict__ fill, int* __restrict__ sorted_eid, int E, int N){
  int e = blockIdx.x*blockDim.x + threadIdx.x;
  if (e < E){
    int d = clampi(ei[E+e], 0, N-1);
    int pos = clampi(indptr[d] + atomicAdd(&fill[d], 1), 0, E-1);
    sorted_eid[pos] = e;
  }
}

// ---------------- node transform GEMM (MFMA): XL = X@Wl+bl, XR = X@Wr+br ----------------
template<int K, int M>
__global__ __launch_bounds__(256) void node_gemm(
    const u16* __restrict__ X, const u16* __restrict__ Wl, const float* __restrict__ blf,
    const u16* __restrict__ Wr, const float* __restrict__ brf,
    u16* __restrict__ XL, u16* __restrict__ XR, int N)
{
  constexpr int KS = K/32;
  int wave = threadIdx.x >> 6, lane = threadIdx.x & 63;
  int ntile = blockIdx.y*4 + wave;
  int mtile = blockIdx.x;
  int m = mtile*16 + (lane & 15);
  if (m >= N) m = N-1;
  int kq = (lane >> 4) * 8;
  int col = ntile*16 + (lane & 15);         // [0, 2M); wave-uniform isR
  bool isR = (col >= M);
  int c = isR ? col - M : col;
  const u16* W = isR ? Wr : Wl;
  float bv = isR ? brf[c] : blf[c];
  u16* OUT = isR ? XR : XL;

  bf16x8 af[KS], bfr[KS];
  const u16* xrow = X + (size_t)m*K;
  #pragma unroll
  for (int s=0; s<KS; s++){
    af[s] = *(const bf16x8*)(xrow + s*32 + kq);                         // A[m][k]
    #pragma unroll
    for (int j=0; j<8; j++) bfr[s][j] = (short)W[(size_t)(s*32 + kq + j)*M + c]; // B[k][n]
  }
  f32x4 acc = {0.f,0.f,0.f,0.f};
  #pragma unroll
  for (int s=0; s<KS; s++)
    acc = __builtin_amdgcn_mfma_f32_16x16x32_bf16(af[s], bfr[s], acc, 0,0,0);
  #pragma unroll
  for (int r=0; r<4; r++){
    int node = mtile*16 + (lane>>4)*4 + r;            // C/D: row=quad*4+reg, col=lane&15
    if (node < N) OUT[(size_t)node*M + c] = f2bf(acc[r] + bv);
  }
}

// ---------------- fused score + online-softmax + aggregate: wave per node ----------------
// We chunk lives in registers (amortized over the node's edges); each xl[src]
// row is gathered ONCE and reused for score and alpha-weighted accumulation.
template<int M>
__global__ __launch_bounds__(256) void fused_score_agg(
    const int* __restrict__ indptr, const int* __restrict__ sorted_eid,
    const int* __restrict__ ei, const u16* __restrict__ eattr,
    const float* __restrict__ wef, const u16* __restrict__ xl,
    const u16* __restrict__ xr, const float* __restrict__ attf,
    const float* __restrict__ biasf, u16* __restrict__ outp, int N, int E)
{
  constexpr int VPT = M/64;
  constexpr int C = M/4;
  int n = blockIdx.x*4 + (threadIdx.x>>6);
  if (n >= N) return;
  int lane = threadIdx.x & 63;
  int c0 = lane*VPT;
  int h = lane>>4;                         // head (both M=256 and M=128)

  float wreg[16][VPT];                     // We[.][c0..c0+VPT) in registers
  #pragma unroll
  for (int k=0;k<16;k++){
    #pragma unroll
    for (int j=0;j<VPT;j++) wreg[k][j] = wef[k*M + c0 + j];
  }
  float at[VPT];
  #pragma unroll
  for (int j=0;j<VPT;j++) at[j] = attf[h*C + (c0&(C-1)) + j];

  float xrv[VPT];
  if constexpr (VPT==4){
    uint2 q = *(const uint2*)(xr + (size_t)n*M + c0);
    xrv[0]=bfbits(q.x<<16); xrv[1]=bfbits(q.x&0xFFFF0000u);
    xrv[2]=bfbits(q.y<<16); xrv[3]=bfbits(q.y&0xFFFF0000u);
  } else {
    u32 q = *(const u32*)(xr + (size_t)n*M + c0);
    xrv[0]=bfbits(q<<16); xrv[1]=bfbits(q&0xFFFF0000u);
  }

  int s0 = clampi(indptr[n],0,E), s1 = clampi(indptr[n+1],s0,E);
  float m = -1e30f, d = 0.f;
  float acc[VPT];
  #pragma unroll
  for (int j=0;j<VPT;j++) acc[j]=0.f;

  for (int i=s0;i<s1;i++){
    int e   = clampi(sorted_eid[i],0,E-1);
    int src = clampi(ei[e],0,N-1);
    float xlv[VPT];
    if constexpr (VPT==4){
      uint2 q = *(const uint2*)(xl + (size_t)src*M + c0);
      xlv[0]=bfbits(q.x<<16); xlv[1]=bfbits(q.x&0xFFFF0000u);
      xlv[2]=bfbits(q.y<<16); xlv[3]=bfbits(q.y&0xFFFF0000u);
    } else {
      u32 q = *(const u32*)(xl + (size_t)src*M + c0);
      xlv[0]=bfbits(q<<16); xlv[1]=bfbits(q&0xFFFF0000u);
    }
    float eaf[16];
    load_eattr16(eattr + (size_t)e*16, eaf);

    float p = 0.f;
    #pragma unroll
    for (int j=0;j<VPT;j++){
      float v = xlv[j] + xrv[j];
      #pragma unroll
      for (int k=0;k<16;k++) v += eaf[k]*wreg[k][j];
      v = (v>0.f)? v : 0.2f*v;
      p += v*at[j];
    }
    p += __shfl_xor(p,1); p += __shfl_xor(p,2); p += __shfl_xor(p,4); p += __shfl_xor(p,8);

    float mn = fmaxf(m, p);
    float sc = __expf(m - mn);             // 0 when m == -1e30
    float wv = __expf(p - mn);
    d = d*sc + wv;
    #pragma unroll
    for (int j=0;j<VPT;j++) acc[j] = acc[j]*sc + wv*xlv[j];
    m = mn;
  }
  float rd = 1.f/(d + 1e-16f);
  #pragma unroll
  for (int j=0;j<VPT;j++){
    float o = acc[j]*rd + biasf[c0+j];
    o = (o>0.f)? o : 0.f;
    outp[(size_t)n*M + c0 + j] = f2bf(o);
  }
}

// ---------------- mean pool + MLP head, one block per graph ----------------
__device__ __forceinline__ int lower_bound_dev(const int* a, int n, int key){
  int lo=0, hi=n;
  while (lo<hi){ int mid=(lo+hi)>>1; if (a[mid] < key) lo=mid+1; else hi=mid; }
  return lo;
}

__global__ __launch_bounds__(128) void pool_mlp_kernel(
    const u16* __restrict__ h2, const int* __restrict__ batch,
    const float* __restrict__ params, const int* __restrict__ flag,
    void* __restrict__ out, int N)
{
  int g = blockIdx.x, t = threadIdx.x;   // 128 threads
  __shared__ int sh_lo, sh_hi;
  if (t==0) sh_lo = lower_bound_dev(batch, N, g);
  if (t==1) sh_hi = lower_bound_dev(batch, N, g+1);
  __syncthreads();
  int lo = clampi(sh_lo, 0, N), hi = clampi(sh_hi, lo, N);
  float s = 0.f;
  for (int n=lo; n<hi; n++) s += bf2f(h2[(size_t)n*128 + t]);
  float cnt = (float)(hi-lo);
  float pooled = s / fmaxf(cnt, 1.f);
  __shared__ float pl[128];
  pl[t] = pooled;
  __syncthreads();
  const float* fc1W = params + 1800;
  float z = 0.f;
  for (int k=0; k<128; k++) z += pl[k]*fc1W[k*128 + t];
  z += params[1536 + t];                 // fc1b
  z = (z>0.f)? z : 0.f;
  __shared__ float red[128];
  red[t] = z * params[1664 + t];         // fc2W
  __syncthreads();
  for (int st=64; st>0; st>>=1){
    if (t<st) red[t] += red[t+st];
    __syncthreads();
  }
  if (t==0){
    float zz = red[0] + params[1792];    // fc2b
    float r = 1.f/(1.f + __expf(-zz));
    if (*flag) ((float*)out)[g] = r;
    else       ((u16*)out)[g] = f2bf(r);
  }
}

// ---------------- launch ----------------
extern "C" void kernel_launch(void* const* d_in, const int* in_sizes, int n_in,
                              void* d_out, int out_size, void* d_ws, size_t ws_size,
                              hipStream_t stream)
{
  const void* x     = d_in[0];
  const void* eattr = d_in[1];
  const int*  ei    = (const int*)d_in[2];
  const int*  batch = (const int*)d_in[3];

  int N = in_sizes[0] / 128;   // 50000
  int E = in_sizes[2] / 2;     // 800000
  int G = out_size;            // 64

  // Workspace layout (256 MB available; peak ~132 MB, no aliasing):
  char* w = (char*)d_ws;
  int*   flag   = (int*)(w);                     // [0,4)
  int*   deg    = (int*)(w + 256);               // N ints
  int*   indptr = (int*)(w + 200448);            // N+1
  int*   sorted = (int*)(w + 400512);            // E ints
  float* we0f   = (float*)(w + 3600640);         // 4096
  float* we1f   = (float*)(w + 3617024);         // 2048
  float* params = (float*)(w + 3658240);         // 18184 f32
  u16*   wbf    = (u16*)(w + 3731200);           // 131072 bf16
  u16*   xbf    = (u16*)(w + 3993600);           // N*128
  u16*   eabf   = (u16*)(w + 16793600);          // E*16
  u16*   xl0    = (u16*)(w + 42393600);          // N*256 (layer1: N*128)
  u16*   xr0    = (u16*)(w + 67993600);          // N*256 (layer1: N*128)
  u16*   h1     = (u16*)(w + 93593600);          // N*256
  u16*   h2     = (u16*)(w + 119193600);         // N*128

  detect_kernel<<<1, 256, 0, stream>>>((const u16*)x, flag);

  int NX4 = N*128/4, NE4 = E*16/4;
  canon_big<<<(NX4+NE4+255)/256, 256, 0, stream>>>(x, eattr, flag,
      (ushort4*)xbf, (ushort4*)eabf, NX4, NE4);
  canon_small<<<(N+255)/256, 256, 0, stream>>>(flag,
      d_in[4], d_in[6], d_in[11], d_in[13],            // Wl0 Wr0 Wl1 Wr1
      d_in[8], d_in[15],                               // We0 We1
      d_in[5], d_in[7], d_in[10], d_in[9],             // bl0 br0 bias0 att0
      d_in[12], d_in[14], d_in[17], d_in[16],          // bl1 br1 bias1 att1
      d_in[19], d_in[20], d_in[21], d_in[18],          // fc1b fc2W fc2b fc1W
      wbf, we0f, we1f, params, deg, N);

  hist_kernel<<<(E+255)/256, 256, 0, stream>>>(ei, deg, E, N);
  scan_kernel<<<1, 1024, 0, stream>>>(deg, indptr, N);
  scatter_kernel<<<(E+255)/256, 256, 0, stream>>>(ei, indptr, deg, sorted, E, N);

  int mt = (N+15)/16;
  // layer 0
  node_gemm<128,256><<<dim3(mt, 8), 256, 0, stream>>>(xbf, wbf, params,
      wbf+32768, params+256, xl0, xr0, N);
  fused_score_agg<256><<<(N+3)/4, 256, 0, stream>>>(indptr, sorted, ei, eabf,
      we0f, xl0, xr0, params+768, params+512, h1, N, E);

  // layer 1
  node_gemm<256,128><<<dim3(mt, 4), 256, 0, stream>>>(h1, wbf+65536, params+1024,
      wbf+98304, params+1152, xl0, xr0, N);
  fused_score_agg<128><<<(N+3)/4, 256, 0, stream>>>(indptr, sorted, ei, eabf,
      we1f, xl0, xr0, params+1408, params+1280, h2, N, E);

  // pool + MLP + sigmoid
  pool_mlp_kernel<<<G, 128, 0, stream>>>(h2, batch, params, flag, d_out, N);
}

// Round 6
// 1309.736 us; speedup vs baseline: 1.4457x; 1.0405x over previous
//
#include <hip/hip_runtime.h>
#include <hip/hip_bf16.h>

typedef unsigned int  u32;
typedef unsigned short u16;
typedef __attribute__((ext_vector_type(8))) short bf16x8;
typedef __attribute__((ext_vector_type(4))) float f32x4;

__device__ __forceinline__ float bfbits(u32 u){ union{u32 i; float f;} v; v.i=u; return v.f; }
__device__ __forceinline__ float bf2f(u16 u){ return bfbits(((u32)u)<<16); }
__device__ __forceinline__ u16 f2bf(float f){
  union{float f; u32 i;} v; v.f=f;
  u32 r = v.i + 0x7FFFu + ((v.i>>16)&1u);
  return (u16)(r>>16);
}
__device__ __forceinline__ int clampi(int v, int lo, int hi){ return v<lo?lo:(v>hi?hi:v); }

// ---------------- dtype detect: bf16 vs fp32 storage (verified r4) ----------------
__global__ void detect_kernel(const u16* __restrict__ xr, int* __restrict__ flag){
  __shared__ int cnt;
  if (threadIdx.x==0) cnt=0;
  __syncthreads();
  int c=0;
  for (int i=threadIdx.x; i<8192; i+=256){
    u16 u = xr[i];
    int e = (u>>7)&0xFF;
    if (e>=0x90 || u==0) c++;
  }
  atomicAdd(&cnt, c);
  __syncthreads();
  if (threadIdx.x==0) *flag = (cnt>16) ? 1 : 0;   // 1 = fp32, 0 = bf16
}

__device__ __forceinline__ float rdin(const void* p, int idx, int f){
  return f ? ((const float*)p)[idx] : bf2f(((const u16*)p)[idx]);
}

// ---------------- canonicalize big tensors: x, edge_attr -> bf16 ----------------
__global__ void canon_big(const void* __restrict__ xr, const void* __restrict__ ear,
                          const int* __restrict__ flag,
                          ushort4* __restrict__ xbf, ushort4* __restrict__ eabf,
                          int NX4, int NE4){
  int f = *flag;
  int i = blockIdx.x*blockDim.x + threadIdx.x;
  if (i < NX4){
    if (f){ const float4 v = ((const float4*)xr)[i];
      ushort4 o; o.x=f2bf(v.x); o.y=f2bf(v.y); o.z=f2bf(v.z); o.w=f2bf(v.w);
      xbf[i]=o;
    } else xbf[i] = ((const ushort4*)xr)[i];
  } else if (i < NX4+NE4){
    int j = i - NX4;
    if (f){ const float4 v = ((const float4*)ear)[j];
      ushort4 o; o.x=f2bf(v.x); o.y=f2bf(v.y); o.z=f2bf(v.z); o.w=f2bf(v.w);
      eabf[j]=o;
    } else eabf[j] = ((const ushort4*)ear)[j];
  }
}

// ---------------- canonicalize small tensors + zero counters ----------------
__global__ void canon_small(const int* __restrict__ flag,
   const void* Wl0, const void* Wr0, const void* Wl1, const void* Wr1,
   const void* We0, const void* We1,
   const void* bl0, const void* br0, const void* bias0, const void* att0,
   const void* bl1, const void* br1, const void* bias1, const void* att1,
   const void* fc1b, const void* fc2W, const void* fc2b, const void* fc1W,
   u16* __restrict__ wbf, float* __restrict__ we0f, float* __restrict__ we1f,
   float* __restrict__ params, int* __restrict__ deg, int N)
{
  int f = *flag;
  int i = blockIdx.x*blockDim.x + threadIdx.x;
  if (i < N) deg[i] = 0;
  if (i < 32768){
    wbf[i]        = f2bf(rdin(Wl0,i,f));
    wbf[32768+i]  = f2bf(rdin(Wr0,i,f));
    wbf[65536+i]  = f2bf(rdin(Wl1,i,f));
    wbf[98304+i]  = f2bf(rdin(Wr1,i,f));
  }
  if (i < 4096) we0f[i] = rdin(We0,i,f);
  if (i < 2048) we1f[i] = rdin(We1,i,f);
  if (i < 256){ params[i]=rdin(bl0,i,f); params[256+i]=rdin(br0,i,f);
                params[512+i]=rdin(bias0,i,f); params[768+i]=rdin(att0,i,f); }
  if (i < 128){ params[1024+i]=rdin(bl1,i,f); params[1152+i]=rdin(br1,i,f);
                params[1280+i]=rdin(bias1,i,f); params[1408+i]=rdin(att1,i,f);
                params[1536+i]=rdin(fc1b,i,f); params[1664+i]=rdin(fc2W,i,f); }
  if (i == 0) params[1792] = rdin(fc2b,0,f);
  if (i < 16384) params[1800+i] = rdin(fc1W,i,f);
}

// ---------------- CSR build ----------------
__global__ void hist_kernel(const int* __restrict__ ei, int* __restrict__ deg, int E, int N){
  int e = blockIdx.x*blockDim.x + threadIdx.x;
  if (e < E) atomicAdd(&deg[clampi(ei[E+e],0,N-1)], 1);
}

// chunked single-pass scan; re-zeroes deg (fill reuse)
__global__ __launch_bounds__(1024) void scan_kernel(int* __restrict__ deg,
                                                    int* __restrict__ indptr, int n){
  __shared__ int lds[1024];
  int t = threadIdx.x;
  int chunk = (n + 1023)/1024;
  int lo = t*chunk, hi = lo+chunk; if (lo>n) lo=n; if (hi>n) hi=n;
  int sum=0;
  for (int i=lo;i<hi;i++) sum += deg[i];
  lds[t]=sum;
  __syncthreads();
  for (int off=1; off<1024; off<<=1){
    int add = (t>=off)? lds[t-off] : 0;
    __syncthreads();
    lds[t] += add;
    __syncthreads();
  }
  int run = lds[t]-sum;
  for (int i=lo;i<hi;i++){
    int v = deg[i]; deg[i]=0;
    indptr[i]=run; run+=v;
  }
  if (lo<n && hi==n) indptr[n]=run;
}

// scatter builds CSR-ordered payloads: src node + eattr row (kills two
// dependent gathers in the hot loop; sorted_eid no longer needed)
__global__ void scatter_kernel(const int* __restrict__ ei, const int* __restrict__ indptr,
                               int* __restrict__ fill, int* __restrict__ csr_src,
                               u16* __restrict__ ea_csr, const u16* __restrict__ eabf,
                               int E, int N){
  int e = blockIdx.x*blockDim.x + threadIdx.x;
  if (e < E){
    int d = clampi(ei[E+e], 0, N-1);
    int pos = clampi(indptr[d] + atomicAdd(&fill[d], 1), 0, E-1);
    csr_src[pos] = clampi(ei[e], 0, N-1);
    const uint4* q = (const uint4*)(eabf + (size_t)e*16);
    uint4 a = q[0], b = q[1];
    uint4* o = (uint4*)(ea_csr + (size_t)pos*16);
    o[0] = a; o[1] = b;
  }
}

// ---------------- node transform GEMM (MFMA): XL = X@Wl+bl, XR = X@Wr+br ----------------
template<int K, int M>
__global__ __launch_bounds__(256) void node_gemm(
    const u16* __restrict__ X, const u16* __restrict__ Wl, const float* __restrict__ blf,
    const u16* __restrict__ Wr, const float* __restrict__ brf,
    u16* __restrict__ XL, u16* __restrict__ XR, int N)
{
  constexpr int KS = K/32;
  int wave = threadIdx.x >> 6, lane = threadIdx.x & 63;
  int ntile = blockIdx.y*4 + wave;
  int mtile = blockIdx.x;
  int m = mtile*16 + (lane & 15);
  if (m >= N) m = N-1;
  int kq = (lane >> 4) * 8;
  int col = ntile*16 + (lane & 15);
  bool isR = (col >= M);
  int c = isR ? col - M : col;
  const u16* W = isR ? Wr : Wl;
  float bv = isR ? brf[c] : blf[c];
  u16* OUT = isR ? XR : XL;

  bf16x8 af[KS], bfr[KS];
  const u16* xrow = X + (size_t)m*K;
  #pragma unroll
  for (int s=0; s<KS; s++){
    af[s] = *(const bf16x8*)(xrow + s*32 + kq);
    #pragma unroll
    for (int j=0; j<8; j++) bfr[s][j] = (short)W[(size_t)(s*32 + kq + j)*M + c];
  }
  f32x4 acc = {0.f,0.f,0.f,0.f};
  #pragma unroll
  for (int s=0; s<KS; s++)
    acc = __builtin_amdgcn_mfma_f32_16x16x32_bf16(af[s], bfr[s], acc, 0,0,0);
  #pragma unroll
  for (int r=0; r<4; r++){
    int node = mtile*16 + (lane>>4)*4 + r;
    if (node < N) OUT[(size_t)node*M + c] = f2bf(acc[r] + bv);
  }
}

// ---------------- fused score + online-softmax + aggregate, chunked by 4 ----------------
// Wave per node. We in registers; CSR-ordered src/eattr streams; 4 xl-gathers
// in flight per chunk; one softmax rescale per chunk (flash-style batched).
template<int M>
__global__ __launch_bounds__(256) void fused_score_agg(
    const int* __restrict__ indptr, const int* __restrict__ csr_src,
    const u16* __restrict__ ea_csr,
    const float* __restrict__ wef, const u16* __restrict__ xl,
    const u16* __restrict__ xr, const float* __restrict__ attf,
    const float* __restrict__ biasf, u16* __restrict__ outp, int N, int E)
{
  constexpr int VPT = M/64;
  constexpr int C = M/4;
  int n = blockIdx.x*4 + (threadIdx.x>>6);
  if (n >= N) return;
  int lane = threadIdx.x & 63;
  int c0 = lane*VPT;
  int h = lane>>4;

  float wreg[16][VPT];
  #pragma unroll
  for (int k=0;k<16;k++)
    #pragma unroll
    for (int j=0;j<VPT;j++) wreg[k][j] = wef[k*M + c0 + j];
  float at[VPT];
  #pragma unroll
  for (int j=0;j<VPT;j++) at[j] = attf[h*C + (c0&(C-1)) + j];

  float xrv[VPT];
  if constexpr (VPT==4){
    uint2 q = *(const uint2*)(xr + (size_t)n*M + c0);
    xrv[0]=bfbits(q.x<<16); xrv[1]=bfbits(q.x&0xFFFF0000u);
    xrv[2]=bfbits(q.y<<16); xrv[3]=bfbits(q.y&0xFFFF0000u);
  } else {
    u32 q = *(const u32*)(xr + (size_t)n*M + c0);
    xrv[0]=bfbits(q<<16); xrv[1]=bfbits(q&0xFFFF0000u);
  }

  int s0 = clampi(indptr[n],0,E), s1 = clampi(indptr[n+1],s0,E);
  float m = -1e30f, d = 0.f;
  float acc[VPT];
  #pragma unroll
  for (int j=0;j<VPT;j++) acc[j]=0.f;

  for (int i=s0; i<s1; i+=4){
    int cnt = s1 - i; if (cnt>4) cnt=4;
    // ---- issue all payload loads (linear streams) ----
    int src[4]; uint4 eaA[4], eaB[4];
    #pragma unroll
    for (int j=0;j<4;j++){
      int idx = (j<cnt)? i+j : i;
      src[j] = csr_src[idx];
      const uint4* q = (const uint4*)(ea_csr + (size_t)idx*16);
      eaA[j] = q[0]; eaB[j] = q[1];
    }
    // ---- issue 4 xl gathers (in flight together) ----
    uint2 xq4[4]; u32 xq2[4];
    #pragma unroll
    for (int j=0;j<4;j++){
      if constexpr (VPT==4) xq4[j] = *(const uint2*)(xl + (size_t)src[j]*M + c0);
      else                  xq2[j] = *(const u32*)(xl + (size_t)src[j]*M + c0);
    }
    // ---- compute 4 scores ----
    float xlv[4][VPT];
    float p[4];
    #pragma unroll
    for (int j=0;j<4;j++){
      if constexpr (VPT==4){
        xlv[j][0]=bfbits(xq4[j].x<<16); xlv[j][1]=bfbits(xq4[j].x&0xFFFF0000u);
        xlv[j][2]=bfbits(xq4[j].y<<16); xlv[j][3]=bfbits(xq4[j].y&0xFFFF0000u);
      } else {
        xlv[j][0]=bfbits(xq2[j]<<16); xlv[j][1]=bfbits(xq2[j]&0xFFFF0000u);
      }
      float v[VPT];
      #pragma unroll
      for (int jj=0;jj<VPT;jj++) v[jj] = xlv[j][jj] + xrv[jj];
      u32 uu[8] = {eaA[j].x,eaA[j].y,eaA[j].z,eaA[j].w,eaB[j].x,eaB[j].y,eaB[j].z,eaB[j].w};
      #pragma unroll
      for (int k=0;k<8;k++){
        float e0 = bfbits(uu[k]<<16), e1 = bfbits(uu[k]&0xFFFF0000u);
        #pragma unroll
        for (int jj=0;jj<VPT;jj++)
          v[jj] += e0*wreg[2*k][jj] + e1*wreg[2*k+1][jj];
      }
      float pp = 0.f;
      #pragma unroll
      for (int jj=0;jj<VPT;jj++){
        float lv = (v[jj]>0.f)? v[jj] : 0.2f*v[jj];
        pp += lv*at[jj];
      }
      pp += __shfl_xor(pp,1); pp += __shfl_xor(pp,2);
      pp += __shfl_xor(pp,4); pp += __shfl_xor(pp,8);
      p[j] = (j<cnt)? pp : -1e30f;
    }
    // ---- batched online-softmax update (one rescale per chunk) ----
    float mn = fmaxf(fmaxf(fmaxf(m,p[0]),fmaxf(p[1],p[2])),p[3]);
    float sc = __expf(m - mn);
    float w0 = __expf(p[0]-mn), w1 = __expf(p[1]-mn);
    float w2 = __expf(p[2]-mn), w3 = __expf(p[3]-mn);
    d = d*sc + (w0+w1) + (w2+w3);
    #pragma unroll
    for (int jj=0;jj<VPT;jj++)
      acc[jj] = acc[jj]*sc + w0*xlv[0][jj] + w1*xlv[1][jj] + w2*xlv[2][jj] + w3*xlv[3][jj];
    m = mn;
  }
  float rd = 1.f/(d + 1e-16f);
  #pragma unroll
  for (int j=0;j<VPT;j++){
    float o = acc[j]*rd + biasf[c0+j];
    o = (o>0.f)? o : 0.f;
    outp[(size_t)n*M + c0 + j] = f2bf(o);
  }
}

// ---------------- mean pool + MLP head, one block per graph ----------------
__device__ __forceinline__ int lower_bound_dev(const int* a, int n, int key){
  int lo=0, hi=n;
  while (lo<hi){ int mid=(lo+hi)>>1; if (a[mid] < key) lo=mid+1; else hi=mid; }
  return lo;
}

__global__ __launch_bounds__(128) void pool_mlp_kernel(
    const u16* __restrict__ h2, const int* __restrict__ batch,
    const float* __restrict__ params, const int* __restrict__ flag,
    void* __restrict__ out, int N)
{
  int g = blockIdx.x, t = threadIdx.x;
  __shared__ int sh_lo, sh_hi;
  if (t==0) sh_lo = lower_bound_dev(batch, N, g);
  if (t==1) sh_hi = lower_bound_dev(batch, N, g+1);
  __syncthreads();
  int lo = clampi(sh_lo, 0, N), hi = clampi(sh_hi, lo, N);
  float s = 0.f;
  for (int n=lo; n<hi; n++) s += bf2f(h2[(size_t)n*128 + t]);
  float cnt = (float)(hi-lo);
  float pooled = s / fmaxf(cnt, 1.f);
  __shared__ float pl[128];
  pl[t] = pooled;
  __syncthreads();
  const float* fc1W = params + 1800;
  float z = 0.f;
  for (int k=0; k<128; k++) z += pl[k]*fc1W[k*128 + t];
  z += params[1536 + t];
  z = (z>0.f)? z : 0.f;
  __shared__ float red[128];
  red[t] = z * params[1664 + t];
  __syncthreads();
  for (int st=64; st>0; st>>=1){
    if (t<st) red[t] += red[t+st];
    __syncthreads();
  }
  if (t==0){
    float zz = red[0] + params[1792];
    float r = 1.f/(1.f + __expf(-zz));
    if (*flag) ((float*)out)[g] = r;
    else       ((u16*)out)[g] = f2bf(r);
  }
}

// ---------------- launch ----------------
extern "C" void kernel_launch(void* const* d_in, const int* in_sizes, int n_in,
                              void* d_out, int out_size, void* d_ws, size_t ws_size,
                              hipStream_t stream)
{
  const void* x     = d_in[0];
  const void* eattr = d_in[1];
  const int*  ei    = (const int*)d_in[2];
  const int*  batch = (const int*)d_in[3];

  int N = in_sizes[0] / 128;   // 50000
  int E = in_sizes[2] / 2;     // 800000
  int G = out_size;            // 64

  // Workspace layout (256 MB available; peak ~158 MB):
  char* w = (char*)d_ws;
  int*   flag    = (int*)(w);                    // [0,4)
  int*   deg     = (int*)(w + 256);              // N ints
  int*   indptr  = (int*)(w + 200448);           // N+1
  int*   csr_src = (int*)(w + 400512);           // E ints
  float* we0f    = (float*)(w + 3600640);        // 4096
  float* we1f    = (float*)(w + 3617024);        // 2048
  float* params  = (float*)(w + 3658240);        // 18184 f32
  u16*   wbf     = (u16*)(w + 3731200);          // 131072 bf16
  u16*   xbf     = (u16*)(w + 3993600);          // N*128
  u16*   eabf    = (u16*)(w + 16793600);         // E*16
  u16*   xl0     = (u16*)(w + 42393600);         // N*256 (layer1: N*128)
  u16*   xr0     = (u16*)(w + 67993600);         // N*256 (layer1: N*128)
  u16*   h1      = (u16*)(w + 93593600);         // N*256
  u16*   h2      = (u16*)(w + 119193600);        // N*128
  u16*   ea_csr  = (u16*)(w + 131993600);        // E*16 (CSR-ordered eattr)

  detect_kernel<<<1, 256, 0, stream>>>((const u16*)x, flag);

  int NX4 = N*128/4, NE4 = E*16/4;
  canon_big<<<(NX4+NE4+255)/256, 256, 0, stream>>>(x, eattr, flag,
      (ushort4*)xbf, (ushort4*)eabf, NX4, NE4);
  canon_small<<<(N+255)/256, 256, 0, stream>>>(flag,
      d_in[4], d_in[6], d_in[11], d_in[13],
      d_in[8], d_in[15],
      d_in[5], d_in[7], d_in[10], d_in[9],
      d_in[12], d_in[14], d_in[17], d_in[16],
      d_in[19], d_in[20], d_in[21], d_in[18],
      wbf, we0f, we1f, params, deg, N);

  hist_kernel<<<(E+255)/256, 256, 0, stream>>>(ei, deg, E, N);
  scan_kernel<<<1, 1024, 0, stream>>>(deg, indptr, N);
  scatter_kernel<<<(E+255)/256, 256, 0, stream>>>(ei, indptr, deg, csr_src, ea_csr, eabf, E, N);

  int mt = (N+15)/16;
  // layer 0
  node_gemm<128,256><<<dim3(mt, 8), 256, 0, stream>>>(xbf, wbf, params,
      wbf+32768, params+256, xl0, xr0, N);
  fused_score_agg<256><<<(N+3)/4, 256, 0, stream>>>(indptr, csr_src, ea_csr,
      we0f, xl0, xr0, params+768, params+512, h1, N, E);

  // layer 1
  node_gemm<256,128><<<dim3(mt, 4), 256, 0, stream>>>(h1, wbf+65536, params+1024,
      wbf+98304, params+1152, xl0, xr0, N);
  fused_score_agg<128><<<(N+3)/4, 256, 0, stream>>>(indptr, csr_src, ea_csr,
      we1f, xl0, xr0, params+1408, params+1280, h2, N, E);

  // pool + MLP + sigmoid
  pool_mlp_kernel<<<G, 128, 0, stream>>>(h2, batch, params, flag, d_out, N);
}

// Round 7
// 1103.648 us; speedup vs baseline: 1.7156x; 1.1867x over previous
//
#include <hip/hip_runtime.h>
#include <hip/hip_bf16.h>

typedef unsigned int  u32;
typedef unsigned short u16;
typedef __attribute__((ext_vector_type(8))) short bf16x8;
typedef __attribute__((ext_vector_type(4))) float f32x4;
typedef __attribute__((ext_vector_type(2))) float f32x2;

__device__ __forceinline__ float bfbits(u32 u){ union{u32 i; float f;} v; v.i=u; return v.f; }
__device__ __forceinline__ float bf2f(u16 u){ return bfbits(((u32)u)<<16); }
__device__ __forceinline__ u16 f2bf(float f){
  union{float f; u32 i;} v; v.f=f;
  u32 r = v.i + 0x7FFFu + ((v.i>>16)&1u);
  return (u16)(r>>16);
}
__device__ __forceinline__ int clampi(int v, int lo, int hi){ return v<lo?lo:(v>hi?hi:v); }
__device__ __forceinline__ f32x2 unpack2(u32 q){
  f32x2 r; r.x = bfbits(q<<16); r.y = bfbits(q&0xFFFF0000u); return r;
}

// ---------------- dtype detect: bf16 vs fp32 storage (verified r4) ----------------
__global__ void detect_kernel(const u16* __restrict__ xr, int* __restrict__ flag){
  __shared__ int cnt;
  if (threadIdx.x==0) cnt=0;
  __syncthreads();
  int c=0;
  for (int i=threadIdx.x; i<8192; i+=256){
    u16 u = xr[i];
    int e = (u>>7)&0xFF;
    if (e>=0x90 || u==0) c++;
  }
  atomicAdd(&cnt, c);
  __syncthreads();
  if (threadIdx.x==0) *flag = (cnt>16) ? 1 : 0;   // 1 = fp32, 0 = bf16
}

__device__ __forceinline__ float rdin(const void* p, int idx, int f){
  return f ? ((const float*)p)[idx] : bf2f(((const u16*)p)[idx]);
}

// ---------------- canonicalize big tensors: x, edge_attr -> bf16 ----------------
__global__ void canon_big(const void* __restrict__ xr, const void* __restrict__ ear,
                          const int* __restrict__ flag,
                          ushort4* __restrict__ xbf, ushort4* __restrict__ eabf,
                          int NX4, int NE4){
  int f = *flag;
  int i = blockIdx.x*blockDim.x + threadIdx.x;
  if (i < NX4){
    if (f){ const float4 v = ((const float4*)xr)[i];
      ushort4 o; o.x=f2bf(v.x); o.y=f2bf(v.y); o.z=f2bf(v.z); o.w=f2bf(v.w);
      xbf[i]=o;
    } else xbf[i] = ((const ushort4*)xr)[i];
  } else if (i < NX4+NE4){
    int j = i - NX4;
    if (f){ const float4 v = ((const float4*)ear)[j];
      ushort4 o; o.x=f2bf(v.x); o.y=f2bf(v.y); o.z=f2bf(v.z); o.w=f2bf(v.w);
      eabf[j]=o;
    } else eabf[j] = ((const ushort4*)ear)[j];
  }
}

// ---------------- canonicalize small tensors + zero counters ----------------
__global__ void canon_small(const int* __restrict__ flag,
   const void* Wl0, const void* Wr0, const void* Wl1, const void* Wr1,
   const void* We0, const void* We1,
   const void* bl0, const void* br0, const void* bias0, const void* att0,
   const void* bl1, const void* br1, const void* bias1, const void* att1,
   const void* fc1b, const void* fc2W, const void* fc2b, const void* fc1W,
   u16* __restrict__ wbf, float* __restrict__ we0f, float* __restrict__ we1f,
   float* __restrict__ params, int* __restrict__ deg, int N)
{
  int f = *flag;
  int i = blockIdx.x*blockDim.x + threadIdx.x;
  if (i < N) deg[i] = 0;
  if (i < 32768){
    wbf[i]        = f2bf(rdin(Wl0,i,f));
    wbf[32768+i]  = f2bf(rdin(Wr0,i,f));
    wbf[65536+i]  = f2bf(rdin(Wl1,i,f));
    wbf[98304+i]  = f2bf(rdin(Wr1,i,f));
  }
  if (i < 4096) we0f[i] = rdin(We0,i,f);
  if (i < 2048) we1f[i] = rdin(We1,i,f);
  if (i < 256){ params[i]=rdin(bl0,i,f); params[256+i]=rdin(br0,i,f);
                params[512+i]=rdin(bias0,i,f); params[768+i]=rdin(att0,i,f); }
  if (i < 128){ params[1024+i]=rdin(bl1,i,f); params[1152+i]=rdin(br1,i,f);
                params[1280+i]=rdin(bias1,i,f); params[1408+i]=rdin(att1,i,f);
                params[1536+i]=rdin(fc1b,i,f); params[1664+i]=rdin(fc2W,i,f); }
  if (i == 0) params[1792] = rdin(fc2b,0,f);
  if (i < 16384) params[1800+i] = rdin(fc1W,i,f);
}

// ---------------- CSR build ----------------
__global__ void hist_kernel(const int* __restrict__ ei, int* __restrict__ deg, int E, int N){
  int e = blockIdx.x*blockDim.x + threadIdx.x;
  if (e < E) atomicAdd(&deg[clampi(ei[E+e],0,N-1)], 1);
}

// chunked single-pass scan; re-zeroes deg (fill reuse)
__global__ __launch_bounds__(1024) void scan_kernel(int* __restrict__ deg,
                                                    int* __restrict__ indptr, int n){
  __shared__ int lds[1024];
  int t = threadIdx.x;
  int chunk = (n + 1023)/1024;
  int lo = t*chunk, hi = lo+chunk; if (lo>n) lo=n; if (hi>n) hi=n;
  int sum=0;
  for (int i=lo;i<hi;i++) sum += deg[i];
  lds[t]=sum;
  __syncthreads();
  for (int off=1; off<1024; off<<=1){
    int add = (t>=off)? lds[t-off] : 0;
    __syncthreads();
    lds[t] += add;
    __syncthreads();
  }
  int run = lds[t]-sum;
  for (int i=lo;i<hi;i++){
    int v = deg[i]; deg[i]=0;
    indptr[i]=run; run+=v;
  }
  if (lo<n && hi==n) indptr[n]=run;
}

// scatter: write only eid (4B) per edge; payload built by csr_payload (linear writes)
__global__ void scatter_kernel(const int* __restrict__ ei, const int* __restrict__ indptr,
                               int* __restrict__ fill, int* __restrict__ eid, int E, int N){
  int e = blockIdx.x*blockDim.x + threadIdx.x;
  if (e < E){
    int d = clampi(ei[E+e], 0, N-1);
    int pos = clampi(indptr[d] + atomicAdd(&fill[d], 1), 0, E-1);
    eid[pos] = e;
  }
}

// pos-parallel payload gather: random 32B READS (L3-resident), linear full-line writes
__global__ void csr_payload(const int* __restrict__ eid, const int* __restrict__ ei,
                            const u16* __restrict__ eabf, int* __restrict__ csr_src,
                            u16* __restrict__ ea_csr, int E, int N){
  int pos = blockIdx.x*blockDim.x + threadIdx.x;
  if (pos < E){
    int e = clampi(eid[pos], 0, E-1);
    csr_src[pos] = clampi(ei[e], 0, N-1);
    const uint4* q = (const uint4*)(eabf + (size_t)e*16);
    uint4 a = q[0], b = q[1];
    uint4* o = (uint4*)(ea_csr + (size_t)pos*16);
    o[0] = a; o[1] = b;
  }
}

// ---------------- node transform GEMM (MFMA): XL = X@Wl+bl, XR = X@Wr+br ----------------
template<int K, int M>
__global__ __launch_bounds__(256) void node_gemm(
    const u16* __restrict__ X, const u16* __restrict__ Wl, const float* __restrict__ blf,
    const u16* __restrict__ Wr, const float* __restrict__ brf,
    u16* __restrict__ XL, u16* __restrict__ XR, int N)
{
  constexpr int KS = K/32;
  int wave = threadIdx.x >> 6, lane = threadIdx.x & 63;
  int ntile = blockIdx.y*4 + wave;
  int mtile = blockIdx.x;
  int m = mtile*16 + (lane & 15);
  if (m >= N) m = N-1;
  int kq = (lane >> 4) * 8;
  int col = ntile*16 + (lane & 15);
  bool isR = (col >= M);
  int c = isR ? col - M : col;
  const u16* W = isR ? Wr : Wl;
  float bv = isR ? brf[c] : blf[c];
  u16* OUT = isR ? XR : XL;

  bf16x8 af[KS], bfr[KS];
  const u16* xrow = X + (size_t)m*K;
  #pragma unroll
  for (int s=0; s<KS; s++){
    af[s] = *(const bf16x8*)(xrow + s*32 + kq);
    #pragma unroll
    for (int j=0; j<8; j++) bfr[s][j] = (short)W[(size_t)(s*32 + kq + j)*M + c];
  }
  f32x4 acc = {0.f,0.f,0.f,0.f};
  #pragma unroll
  for (int s=0; s<KS; s++)
    acc = __builtin_amdgcn_mfma_f32_16x16x32_bf16(af[s], bfr[s], acc, 0,0,0);
  #pragma unroll
  for (int r=0; r<4; r++){
    int node = mtile*16 + (lane>>4)*4 + r;
    if (node < N) OUT[(size_t)node*M + c] = f2bf(acc[r] + bv);
  }
}

// ---------------- fused score + online-softmax + aggregate, chunked by 4 ----------------
// Wave per node; We/att/bias in registers; packed-f32 (v_pk_fma_f32) arithmetic.
template<int M>
__global__ __launch_bounds__(256) void fused_score_agg(
    const int* __restrict__ indptr, const int* __restrict__ csr_src,
    const u16* __restrict__ ea_csr,
    const float* __restrict__ wef, const u16* __restrict__ xl,
    const u16* __restrict__ xr, const float* __restrict__ attf,
    const float* __restrict__ biasf, u16* __restrict__ outp, int N, int E)
{
  constexpr int VPT = M/64;       // 4 (M=256) or 2 (M=128)
  constexpr int VP2 = VPT/2;      // f32x2 count per lane
  constexpr int C = M/4;
  int n = blockIdx.x*4 + (threadIdx.x>>6);
  if (n >= N) return;
  int lane = threadIdx.x & 63;
  int c0 = lane*VPT;
  int h = lane>>4;

  f32x2 w2[16][VP2];
  #pragma unroll
  for (int k=0;k<16;k++)
    #pragma unroll
    for (int q=0;q<VP2;q++) w2[k][q] = *(const f32x2*)(wef + k*M + c0 + 2*q);
  f32x2 at2[VP2];
  #pragma unroll
  for (int q=0;q<VP2;q++) at2[q] = *(const f32x2*)(attf + h*C + (c0&(C-1)) + 2*q);
  f32x2 b2[VP2];
  #pragma unroll
  for (int q=0;q<VP2;q++) b2[q] = *(const f32x2*)(biasf + c0 + 2*q);

  f32x2 xrv2[VP2];
  if constexpr (VPT==4){
    uint2 q = *(const uint2*)(xr + (size_t)n*M + c0);
    xrv2[0] = unpack2(q.x); xrv2[1] = unpack2(q.y);
  } else {
    u32 q = *(const u32*)(xr + (size_t)n*M + c0);
    xrv2[0] = unpack2(q);
  }

  int s0 = clampi(indptr[n],0,E), s1 = clampi(indptr[n+1],s0,E);
  float m = -1e30f, d = 0.f;
  f32x2 acc2[VP2];
  #pragma unroll
  for (int q=0;q<VP2;q++) acc2[q] = (f32x2){0.f,0.f};

  for (int i=s0; i<s1; i+=4){
    int cnt = s1 - i; if (cnt>4) cnt=4;
    // ---- payload loads (linear streams) ----
    int src[4]; uint4 eaA[4], eaB[4];
    #pragma unroll
    for (int j=0;j<4;j++){
      int idx = (j<cnt)? i+j : i;
      src[j] = csr_src[idx];
      const uint4* qp = (const uint4*)(ea_csr + (size_t)idx*16);
      eaA[j] = qp[0]; eaB[j] = qp[1];
    }
    // ---- 4 xl gathers in flight ----
    uint2 xq4[4]; u32 xq2[4];
    #pragma unroll
    for (int j=0;j<4;j++){
      if constexpr (VPT==4) xq4[j] = *(const uint2*)(xl + (size_t)src[j]*M + c0);
      else                  xq2[j] = *(const u32*)(xl + (size_t)src[j]*M + c0);
    }
    // ---- 4 scores (packed f32 math) ----
    f32x2 xlv2[4][VP2];
    float p[4];
    #pragma unroll
    for (int j=0;j<4;j++){
      if constexpr (VPT==4){
        xlv2[j][0] = unpack2(xq4[j].x); xlv2[j][1] = unpack2(xq4[j].y);
      } else {
        xlv2[j][0] = unpack2(xq2[j]);
      }
      f32x2 v2[VP2];
      #pragma unroll
      for (int q=0;q<VP2;q++) v2[q] = xlv2[j][q] + xrv2[q];
      u32 uu[8] = {eaA[j].x,eaA[j].y,eaA[j].z,eaA[j].w,eaB[j].x,eaB[j].y,eaB[j].z,eaB[j].w};
      #pragma unroll
      for (int k=0;k<8;k++){
        f32x2 ep = unpack2(uu[k]);
        f32x2 e0v = {ep.x, ep.x}, e1v = {ep.y, ep.y};
        #pragma unroll
        for (int q=0;q<VP2;q++){
          v2[q] = __builtin_elementwise_fma(e0v, w2[2*k][q],   v2[q]);
          v2[q] = __builtin_elementwise_fma(e1v, w2[2*k+1][q], v2[q]);
        }
      }
      f32x2 pa = {0.f,0.f};
      #pragma unroll
      for (int q=0;q<VP2;q++){
        f32x2 lv = __builtin_elementwise_max(v2[q], v2[q]*0.2f);
        pa = __builtin_elementwise_fma(lv, at2[q], pa);
      }
      float pp = pa.x + pa.y;
      pp += __shfl_xor(pp,1); pp += __shfl_xor(pp,2);
      pp += __shfl_xor(pp,4); pp += __shfl_xor(pp,8);
      if constexpr (M==256) pp += __shfl_xor(pp,16)*0.f;  // reduce width 16 both cases
      p[j] = (j<cnt)? pp : -1e30f;
    }
    // ---- batched online-softmax update ----
    float mn = fmaxf(fmaxf(fmaxf(m,p[0]),fmaxf(p[1],p[2])),p[3]);
    float sc = __expf(m - mn);
    float w0 = __expf(p[0]-mn), w1 = __expf(p[1]-mn);
    float w2s = __expf(p[2]-mn), w3 = __expf(p[3]-mn);
    d = d*sc + (w0+w1) + (w2s+w3);
    f32x2 scv = {sc,sc};
    f32x2 wv0 = {w0,w0}, wv1 = {w1,w1}, wv2 = {w2s,w2s}, wv3 = {w3,w3};
    #pragma unroll
    for (int q=0;q<VP2;q++){
      f32x2 a = acc2[q]*scv;
      a = __builtin_elementwise_fma(wv0, xlv2[0][q], a);
      a = __builtin_elementwise_fma(wv1, xlv2[1][q], a);
      a = __builtin_elementwise_fma(wv2, xlv2[2][q], a);
      a = __builtin_elementwise_fma(wv3, xlv2[3][q], a);
      acc2[q] = a;
    }
    m = mn;
  }
  float rd = 1.f/(d + 1e-16f);
  f32x2 rdv = {rd, rd};
  #pragma unroll
  for (int q=0;q<VP2;q++){
    f32x2 o = __builtin_elementwise_fma(acc2[q], rdv, b2[q]);
    o = __builtin_elementwise_max(o, (f32x2){0.f,0.f});
    outp[(size_t)n*M + c0 + 2*q    ] = f2bf(o.x);
    outp[(size_t)n*M + c0 + 2*q + 1] = f2bf(o.y);
  }
}

// ---------------- mean pool + MLP head, one block per graph ----------------
__device__ __forceinline__ int lower_bound_dev(const int* a, int n, int key){
  int lo=0, hi=n;
  while (lo<hi){ int mid=(lo+hi)>>1; if (a[mid] < key) lo=mid+1; else hi=mid; }
  return lo;
}

__global__ __launch_bounds__(128) void pool_mlp_kernel(
    const u16* __restrict__ h2, const int* __restrict__ batch,
    const float* __restrict__ params, const int* __restrict__ flag,
    void* __restrict__ out, int N)
{
  int g = blockIdx.x, t = threadIdx.x;
  __shared__ int sh_lo, sh_hi;
  if (t==0) sh_lo = lower_bound_dev(batch, N, g);
  if (t==1) sh_hi = lower_bound_dev(batch, N, g+1);
  __syncthreads();
  int lo = clampi(sh_lo, 0, N), hi = clampi(sh_hi, lo, N);
  float s0=0.f,s1=0.f,s2=0.f,s3=0.f,s4=0.f,s5=0.f,s6=0.f,s7=0.f;
  int n = lo;
  for (; n+8<=hi; n+=8){
    s0 += bf2f(h2[(size_t)(n+0)*128 + t]);
    s1 += bf2f(h2[(size_t)(n+1)*128 + t]);
    s2 += bf2f(h2[(size_t)(n+2)*128 + t]);
    s3 += bf2f(h2[(size_t)(n+3)*128 + t]);
    s4 += bf2f(h2[(size_t)(n+4)*128 + t]);
    s5 += bf2f(h2[(size_t)(n+5)*128 + t]);
    s6 += bf2f(h2[(size_t)(n+6)*128 + t]);
    s7 += bf2f(h2[(size_t)(n+7)*128 + t]);
  }
  for (; n<hi; n++) s0 += bf2f(h2[(size_t)n*128 + t]);
  float s = ((s0+s1)+(s2+s3)) + ((s4+s5)+(s6+s7));
  float cnt = (float)(hi-lo);
  float pooled = s / fmaxf(cnt, 1.f);
  __shared__ float pl[128];
  pl[t] = pooled;
  __syncthreads();
  const float* fc1W = params + 1800;
  float z = 0.f;
  for (int k=0; k<128; k++) z += pl[k]*fc1W[k*128 + t];
  z += params[1536 + t];
  z = (z>0.f)? z : 0.f;
  __shared__ float red[128];
  red[t] = z * params[1664 + t];
  __syncthreads();
  for (int st=64; st>0; st>>=1){
    if (t<st) red[t] += red[t+st];
    __syncthreads();
  }
  if (t==0){
    float zz = red[0] + params[1792];
    float r = 1.f/(1.f + __expf(-zz));
    if (*flag) ((float*)out)[g] = r;
    else       ((u16*)out)[g] = f2bf(r);
  }
}

// ---------------- launch ----------------
extern "C" void kernel_launch(void* const* d_in, const int* in_sizes, int n_in,
                              void* d_out, int out_size, void* d_ws, size_t ws_size,
                              hipStream_t stream)
{
  const void* x     = d_in[0];
  const void* eattr = d_in[1];
  const int*  ei    = (const int*)d_in[2];
  const int*  batch = (const int*)d_in[3];

  int N = in_sizes[0] / 128;   // 50000
  int E = in_sizes[2] / 2;     // 800000
  int G = out_size;            // 64

  // Workspace layout (256 MB available; peak ~161 MB):
  char* w = (char*)d_ws;
  int*   flag    = (int*)(w);                    // [0,4)
  int*   deg     = (int*)(w + 256);              // N ints
  int*   indptr  = (int*)(w + 200448);           // N+1
  int*   csr_src = (int*)(w + 400512);           // E ints
  float* we0f    = (float*)(w + 3600640);        // 4096
  float* we1f    = (float*)(w + 3617024);        // 2048
  float* params  = (float*)(w + 3658240);        // 18184 f32
  u16*   wbf     = (u16*)(w + 3731200);          // 131072 bf16
  u16*   xbf     = (u16*)(w + 3993600);          // N*128
  u16*   eabf    = (u16*)(w + 16793600);         // E*16
  u16*   xl0     = (u16*)(w + 42393600);         // N*256 (layer1: N*128)
  u16*   xr0     = (u16*)(w + 67993600);         // N*256 (layer1: N*128)
  u16*   h1      = (u16*)(w + 93593600);         // N*256
  u16*   h2      = (u16*)(w + 119193600);        // N*128
  u16*   ea_csr  = (u16*)(w + 131993600);        // E*16 (CSR-ordered eattr)
  int*   eid     = (int*)(w + 157593600);        // E ints (CSR-ordered edge id)

  detect_kernel<<<1, 256, 0, stream>>>((const u16*)x, flag);

  int NX4 = N*128/4, NE4 = E*16/4;
  canon_big<<<(NX4+NE4+255)/256, 256, 0, stream>>>(x, eattr, flag,
      (ushort4*)xbf, (ushort4*)eabf, NX4, NE4);
  canon_small<<<(N+255)/256, 256, 0, stream>>>(flag,
      d_in[4], d_in[6], d_in[11], d_in[13],
      d_in[8], d_in[15],
      d_in[5], d_in[7], d_in[10], d_in[9],
      d_in[12], d_in[14], d_in[17], d_in[16],
      d_in[19], d_in[20], d_in[21], d_in[18],
      wbf, we0f, we1f, params, deg, N);

  hist_kernel<<<(E+255)/256, 256, 0, stream>>>(ei, deg, E, N);
  scan_kernel<<<1, 1024, 0, stream>>>(deg, indptr, N);
  scatter_kernel<<<(E+255)/256, 256, 0, stream>>>(ei, indptr, deg, eid, E, N);
  csr_payload<<<(E+255)/256, 256, 0, stream>>>(eid, ei, eabf, csr_src, ea_csr, E, N);

  int mt = (N+15)/16;
  // layer 0
  node_gemm<128,256><<<dim3(mt, 8), 256, 0, stream>>>(xbf, wbf, params,
      wbf+32768, params+256, xl0, xr0, N);
  fused_score_agg<256><<<(N+3)/4, 256, 0, stream>>>(indptr, csr_src, ea_csr,
      we0f, xl0, xr0, params+768, params+512, h1, N, E);

  // layer 1
  node_gemm<256,128><<<dim3(mt, 4), 256, 0, stream>>>(h1, wbf+65536, params+1024,
      wbf+98304, params+1152, xl0, xr0, N);
  fused_score_agg<128><<<(N+3)/4, 256, 0, stream>>>(indptr, csr_src, ea_csr,
      we1f, xl0, xr0, params+1408, params+1280, h2, N, E);

  // pool + MLP + sigmoid
  pool_mlp_kernel<<<G, 128, 0, stream>>>(h2, batch, params, flag, d_out, N);
}